// Round 16
// baseline (33.308 us; speedup 1.0000x reference)
//
#include <hip/hip_runtime.h>
#include <hip/hip_bf16.h>
#include <hip/hip_fp16.h>

#define NN 2000
#define DD 24
#define JA 576
#define WROWH 640             // halves per l-row: 576 beta + 4 x 16 (alpha6,diag6,pad4) = 1280 B
#define ALPH 576
#define IDXCAP 2048           // two 1024-entry segments per row
#define SEGC 1024
#define THRESH 10.0f          // keep pair if S - max_j diff_j^2 <= THRESH (K >= e^-10)
#define PREP_BLOCKS 320       // 32 x 10
#define PASSA_BLOCKS 1000     // 2 l's x 2 segments per block

__device__ __forceinline__ float2 h2f(float f) {
    union { float f; __half2 h; } u; u.f = f;
    return __half22float2(u.h);
}

// ================= merged prep (fp16 Wf build) + passA (survivor lists, 2-seg split) =====
// Wf[l][640h]: [j*24+a] = 2*beta[j][a][l]; tail per jgroup g at 576+g*16:
//   [0..5] alpha[6g..6g+5][l], [6..11] 2*beta[j][j][l], [12..15] pad.
// Survivor predicate symmetric in (i,l) => per-l ascending partner list, split into
// seg0 (i<1024, at row[0..]) and seg1 (i>=1024, at row[1024..]); cnt2[2l+seg].
__global__ __launch_bounds__(256) void k_prepA(const float* __restrict__ beta,
                                               const float* __restrict__ alpha,
                                               const float* __restrict__ x,
                                               __half* __restrict__ Wf,
                                               int* __restrict__ cnt2,
                                               unsigned short* __restrict__ idx) {
    const int tid = threadIdx.x;
    if (blockIdx.x < PREP_BLOCKS) {
        const int xb = blockIdx.x & 31, yb = blockIdx.x >> 5;   // 32 x 10
        const int tx = tid & 63, ty = tid >> 6;
        if (yb < 9) {
            __shared__ float t[64][65];
            const int l0 = xb * 64, ja0 = yb * 64;
            for (int r = ty; r < 64; r += 4) {
                int ja = ja0 + r, l = l0 + tx;
                if (ja < JA && l < NN) t[r][tx] = 2.0f * beta[(size_t)ja * NN + l];
            }
            __syncthreads();
            for (int r = ty; r < 64; r += 4) {
                int l = l0 + r, ja = ja0 + tx;
                if (l < NN && ja < JA)
                    Wf[(size_t)l * WROWH + ja] = __float2half(t[tx][r]);
            }
        } else {
            int l = xb * 64 + (tid & 63);
            int g = tid >> 6;                 // 0..3 -> j = 6g..6g+5
            if (l < NN) {
                __half* w = Wf + (size_t)l * WROWH + ALPH + g * 16;
                #pragma unroll
                for (int q = 0; q < 6; ++q) {
                    int j = g * 6 + q;
                    w[q]     = __float2half(alpha[(size_t)j * NN + l]);
                    w[6 + q] = __float2half(2.0f * beta[(size_t)(j * DD + j) * NN + l]);
                }
                w[12] = w[13] = w[14] = w[15] = __float2half(0.f);
            }
        }
    } else {
        const int pa = blockIdx.x - PREP_BLOCKS;       // 0..999
        const int wave = tid >> 6, lane = tid & 63;
        const int l = pa * 2 + (wave >> 1);            // 0..1999 (row owner)
        const int seg = wave & 1;                      // 0: i<1024, 1: i>=1024
        float xl[DD];
        {
            const float* xr = x + (size_t)l * DD;
            #pragma unroll
            for (int k = 0; k < DD; ++k) xl[k] = xr[k];
        }
        unsigned short* row = idx + (size_t)l * IDXCAP + seg * SEGC;
        int base = 0;
        const int c0 = seg * 16;
        for (int c = c0; c < c0 + 16; ++c) {
            int i = c * 64 + lane;
            bool valid = i < NN;
            int ic = valid ? i : 0;
            const float4* xv = reinterpret_cast<const float4*>(x + (size_t)ic * DD);
            float S = 0.f, m2 = 0.f;
            #pragma unroll
            for (int q = 0; q < 6; ++q) {
                float4 v = xv[q];
                float d0 = v.x - xl[4*q+0], d1 = v.y - xl[4*q+1];
                float d2 = v.z - xl[4*q+2], d3 = v.w - xl[4*q+3];
                d0 *= d0; d1 *= d1; d2 *= d2; d3 *= d3;
                S += (d0 + d1) + (d2 + d3);
                m2 = fmaxf(m2, fmaxf(fmaxf(d0, d1), fmaxf(d2, d3)));
            }
            bool pred = valid && (S - m2 <= THRESH);
            unsigned long long mask = __ballot(pred);
            if (pred) {
                int rank = __popcll(mask & ((1ull << lane) - 1ull));
                row[base + rank] = (unsigned short)i;
            }
            base += __popcll(mask);
        }
        if (lane == 0) cnt2[2 * l + seg] = base;
    }
}

// ================= pass B: block = one i; 4 waves = 4 jgroups; lanes = entries ==========
// Entries are the concatenation of seg0 [0..c0) and seg1 [1024..1024+c1) -> same
// ascending order and lane->entry map as the unsplit list (bit-identical output).
// All W reads are 16-B float4 (dwordx4); halves unpacked via bit-cast.
template <int J0>
__device__ __forceinline__ void waveB(const float* __restrict__ x,
                                      const __half* __restrict__ Wf,
                                      const unsigned short* __restrict__ row,
                                      int c0, int ctot, const float (&xi)[DD],
                                      int lane, float* __restrict__ out, int i) {
    constexpr int g = J0 / 6;
    float acc[6];
    #pragma unroll
    for (int q = 0; q < 6; ++q) acc[q] = 0.0f;

    #pragma unroll 1
    for (int e = lane; e < ctot; e += 64) {
        const int ee = e < c0 ? e : e - c0 + SEGC;
        const int l = row[ee];
        const float4* __restrict__ xv = reinterpret_cast<const float4*>(x + (size_t)l * DD);
        const float4* __restrict__ wv = reinterpret_cast<const float4*>(Wf + (size_t)l * WROWH);

        // tail: 2 x float4 -> alpha[6], diag[6]
        float4 ta = wv[72 + 2 * g];
        float4 tb = wv[72 + 2 * g + 1];
        float2 a01 = h2f(ta.x), a23 = h2f(ta.y), a45 = h2f(ta.z);
        float2 d01 = h2f(ta.w), d23 = h2f(tb.x), d45 = h2f(tb.y);
        float alp[6] = {a01.x, a01.y, a23.x, a23.y, a45.x, a45.y};
        float dia[6] = {d01.x, d01.y, d23.x, d23.y, d45.x, d45.y};

        float diff[DD];
        float negS = 0.f;
        #pragma unroll
        for (int q = 0; q < 6; ++q) {
            float4 vv = xv[q];
            float d0 = xi[4*q+0] - vv.x, d1 = xi[4*q+1] - vv.y;
            float d2 = xi[4*q+2] - vv.z, d3 = xi[4*q+3] - vv.w;
            diff[4*q+0] = d0; diff[4*q+1] = d1;
            diff[4*q+2] = d2; diff[4*q+3] = d3;
            negS = fmaf(-d0, d0, negS); negS = fmaf(-d1, d1, negS);
            negS = fmaf(-d2, d2, negS); negS = fmaf(-d3, d3, negS);
        }

        #pragma unroll
        for (int q = 0; q < 6; ++q) {
            const int j = J0 + q;                        // compile-time
            float dj = diff[j];
            float K = __expf(fmaf(dj, dj, negS));        // exp(diff_j^2 - S)
            float4 b0 = wv[j * 3 + 0];                   // 3 x dwordx4 = 24 halves
            float4 b1 = wv[j * 3 + 1];
            float4 b2 = wv[j * 3 + 2];
            float t0 = 0.f, t1 = 0.f, t2 = 0.f, t3 = 0.f;
            float2 p;
            p = h2f(b0.x); t0 = fmaf(p.x, diff[0],  t0); t1 = fmaf(p.y, diff[1],  t1);
            p = h2f(b0.y); t2 = fmaf(p.x, diff[2],  t2); t3 = fmaf(p.y, diff[3],  t3);
            p = h2f(b0.z); t0 = fmaf(p.x, diff[4],  t0); t1 = fmaf(p.y, diff[5],  t1);
            p = h2f(b0.w); t2 = fmaf(p.x, diff[6],  t2); t3 = fmaf(p.y, diff[7],  t3);
            p = h2f(b1.x); t0 = fmaf(p.x, diff[8],  t0); t1 = fmaf(p.y, diff[9],  t1);
            p = h2f(b1.y); t2 = fmaf(p.x, diff[10], t2); t3 = fmaf(p.y, diff[11], t3);
            p = h2f(b1.z); t0 = fmaf(p.x, diff[12], t0); t1 = fmaf(p.y, diff[13], t1);
            p = h2f(b1.w); t2 = fmaf(p.x, diff[14], t2); t3 = fmaf(p.y, diff[15], t3);
            p = h2f(b2.x); t0 = fmaf(p.x, diff[16], t0); t1 = fmaf(p.y, diff[17], t1);
            p = h2f(b2.y); t2 = fmaf(p.x, diff[18], t2); t3 = fmaf(p.y, diff[19], t3);
            p = h2f(b2.z); t0 = fmaf(p.x, diff[20], t0); t1 = fmaf(p.y, diff[21], t1);
            p = h2f(b2.w); t2 = fmaf(p.x, diff[22], t2); t3 = fmaf(p.y, diff[23], t3);
            float t = (t0 + t1) + (t2 + t3);
            t = fmaf(-dia[q], dj, t);                    // drop a==j
            acc[q] += K * (alp[q] + t);
        }
    }

    // tree-reduce across 64 lanes (fixed order -> deterministic)
    #pragma unroll
    for (int q = 0; q < 6; ++q) {
        float v = acc[q];
        #pragma unroll
        for (int m = 1; m < 64; m <<= 1)
            v += __shfl_xor(v, m, 64);
        acc[q] = v;
    }
    if (lane == 0) {
        #pragma unroll
        for (int q = 0; q < 6; ++q)
            out[(size_t)i * DD + J0 + q] = acc[q];
    }
}

__global__ __launch_bounds__(256, 4) void k_passB(const float* __restrict__ x,
                                                  const __half* __restrict__ Wf,
                                                  const int* __restrict__ cnt2,
                                                  const unsigned short* __restrict__ idx,
                                                  float* __restrict__ out) {
    const int i = blockIdx.x;                  // 0..1999
    const int wave = threadIdx.x >> 6, lane = threadIdx.x & 63;

    float xi[DD];
    {
        const float4* xr = reinterpret_cast<const float4*>(x + (size_t)i * DD);
        #pragma unroll
        for (int q = 0; q < 6; ++q) {
            float4 v = xr[q];
            xi[4*q+0] = v.x; xi[4*q+1] = v.y; xi[4*q+2] = v.z; xi[4*q+3] = v.w;
        }
    }
    const int c0 = cnt2[2 * i];
    const int ctot = c0 + cnt2[2 * i + 1];
    const unsigned short* row = idx + (size_t)i * IDXCAP;

    if      (wave == 0) waveB<0 >(x, Wf, row, c0, ctot, xi, lane, out, i);
    else if (wave == 1) waveB<6 >(x, Wf, row, c0, ctot, xi, lane, out, i);
    else if (wave == 2) waveB<12>(x, Wf, row, c0, ctot, xi, lane, out, i);
    else                waveB<18>(x, Wf, row, c0, ctot, xi, lane, out, i);
}

// ================= dense fallback (never taken in practice; Wf layout) =================
template <int J0>
__device__ __forceinline__ void run_j6(const float* __restrict__ x,
                                       const __half* __restrict__ Wf,
                                       float* __restrict__ part,
                                       const float (&xi)[DD],
                                       int i, int lb, int l0, int l1) {
    constexpr int g = J0 / 6;
    float acc[6];
    #pragma unroll
    for (int q = 0; q < 6; ++q) acc[q] = 0.0f;
    #pragma unroll 1
    for (int l = l0; l < l1; ++l) {
        const __half* __restrict__ wrow = Wf + (size_t)l * WROWH;
        const float* __restrict__ xl = x + (size_t)l * DD;
        float diff[DD]; float negS = 0.0f;
        #pragma unroll
        for (int k = 0; k < DD; ++k) {
            float d = xi[k] - xl[k];
            diff[k] = d; negS = fmaf(-d, d, negS);
        }
        #pragma unroll
        for (int q = 0; q < 6; ++q) {
            const int j = J0 + q;
            float dj = diff[j];
            float K = __expf(fmaf(dj, dj, negS));
            float t = 0.f;
            #pragma unroll
            for (int a = 0; a < DD; ++a)
                t = fmaf(__half2float(wrow[j * DD + a]), diff[a], t);
            t = fmaf(-__half2float(wrow[ALPH + g * 16 + 6 + q]), dj, t);
            acc[q] = fmaf(K, __half2float(wrow[ALPH + g * 16 + q]) + t, acc[q]);
        }
    }
    if (i < NN) {
        #pragma unroll
        for (int q = 0; q < 6; ++q)
            part[((size_t)lb * DD + (J0+q)) * NN + i] = acc[q];
    }
}

__global__ __launch_bounds__(256, 4) void k_pass1_js(const float* __restrict__ x,
                                                     const __half* __restrict__ Wf,
                                                     float* __restrict__ part,
                                                     int lch) {
    const int tid  = threadIdx.x;
    const int wave = tid >> 6, lane = tid & 63;
    const int i  = blockIdx.x * 64 + lane;
    const int ic = i < NN ? i : NN - 1;
    const int lb = blockIdx.y;
    float xi[DD];
    {
        const float4* xr = reinterpret_cast<const float4*>(x + (size_t)ic * DD);
        #pragma unroll
        for (int q = 0; q < DD/4; ++q) {
            float4 v = xr[q];
            xi[4*q+0]=v.x; xi[4*q+1]=v.y; xi[4*q+2]=v.z; xi[4*q+3]=v.w;
        }
    }
    const int l0 = lb * lch;
    int l1 = l0 + lch; if (l1 > NN) l1 = NN;
    if      (wave == 0) run_j6<0 >(x, Wf, part, xi, i, lb, l0, l1);
    else if (wave == 1) run_j6<6 >(x, Wf, part, xi, i, lb, l0, l1);
    else if (wave == 2) run_j6<12>(x, Wf, part, xi, i, lb, l0, l1);
    else                run_j6<18>(x, Wf, part, xi, i, lb, l0, l1);
}

__global__ __launch_bounds__(256) void k_pass2t(const float* __restrict__ part,
                                                float* __restrict__ out, int lblk) {
    int m = blockIdx.x * 256 + threadIdx.x;
    if (m >= NN * DD) return;
    float s = 0.0f;
    for (int b = 0; b < lblk; ++b)
        s += part[(size_t)b * (NN * DD) + m];
    int j = m / NN, i = m - j * NN;
    out[(size_t)i * DD + j] = s;
}
// ================= end fallback =================

extern "C" void kernel_launch(void* const* d_in, const int* in_sizes, int n_in,
                              void* d_out, int out_size, void* d_ws, size_t ws_size,
                              hipStream_t stream) {
    const float* x     = (const float*)d_in[0];   // [2000, 24]
    const float* alpha = (const float*)d_in[1];   // [24, 2000]
    const float* beta  = (const float*)d_in[2];   // [24, 24, 2000]
    float* out = (float*)d_out;                   // [2000, 24]

    const size_t WBYTES    = (size_t)NN * WROWH * 2;               // 2,560,000
    const size_t CNT_OFF   = WBYTES;
    const size_t IDX_OFF   = CNT_OFF + 16384;                      // cnt2: 2*NN ints
    const size_t IDXBYTES  = (size_t)NN * IDXCAP * 2;              // 8,192,000
    const size_t NEED = IDX_OFF + IDXBYTES;                        // ~10.8 MB

    __half* Wf = (__half*)d_ws;

    if (ws_size >= NEED) {
        int* cnt2 = (int*)((char*)d_ws + CNT_OFF);
        unsigned short* idx = (unsigned short*)((char*)d_ws + IDX_OFF);

        k_prepA<<<PREP_BLOCKS + PASSA_BLOCKS, 256, 0, stream>>>(beta, alpha, x, Wf, cnt2, idx);
        k_passB<<<NN, 256, 0, stream>>>(x, Wf, cnt2, idx, out);
    } else {
        // dense fallback (unlikely: ws proven ~268 MB)
        const size_t SLAB = (size_t)NN * DD * 4;
        float* part = (float*)((char*)d_ws + IDX_OFF);
        int lblk = 32;
        while (lblk > 1 && IDX_OFF + (size_t)lblk * SLAB > ws_size) lblk >>= 1;
        int lch = (NN + lblk - 1) / lblk;
        int* cnt2 = (int*)((char*)d_ws + CNT_OFF);
        unsigned short* dummy = (unsigned short*)((char*)d_ws + CNT_OFF);
        k_prepA<<<PREP_BLOCKS, 256, 0, stream>>>(beta, alpha, x, Wf, cnt2, dummy);
        k_pass1_js<<<dim3(32, lblk), 256, 0, stream>>>(x, Wf, part, lch);
        k_pass2t<<<(NN * DD + 255) / 256, 256, 0, stream>>>(part, out, lblk);
    }
}

// Round 17
// 31.838 us; speedup vs baseline: 1.0462x; 1.0462x over previous
//
#include <hip/hip_runtime.h>
#include <hip/hip_bf16.h>
#include <hip/hip_fp16.h>

#define NN 2000
#define DD 24
#define JA 576
#define WROWH 640             // halves per l-row: 576 beta + 4 x 16 (alpha6,diag6,pad4) = 1280 B
#define ALPH 576
#define IDXCAP 2048           // >= NN, rows can never overflow
#define THRESH 10.0f          // keep pair if S - max_j diff_j^2 <= THRESH (K >= e^-10)
#define PREP_BLOCKS 320       // 32 x 10

__device__ __forceinline__ float2 h2f(float f) {
    union { float f; __half2 h; } u; u.f = f;
    return __half22float2(u.h);
}

// ================= merged prep (fp16 Wf build) + passA (survivor lists) =================
// Wf[l][640h]: [j*24+a] = 2*beta[j][a][l]; tail per jgroup g at 576+g*16:
//   [0..5] alpha[6g..6g+5][l], [6..11] 2*beta[j][j][l], [12..15] pad.
// Survivor predicate symmetric in (i,l) => row[i] = ascending partner list of i; cnt[i].
__global__ __launch_bounds__(256) void k_prepA(const float* __restrict__ beta,
                                               const float* __restrict__ alpha,
                                               const float* __restrict__ x,
                                               __half* __restrict__ Wf,
                                               int* __restrict__ cnt,
                                               unsigned short* __restrict__ idx) {
    const int tid = threadIdx.x;
    if (blockIdx.x < PREP_BLOCKS) {
        const int xb = blockIdx.x & 31, yb = blockIdx.x >> 5;   // 32 x 10
        const int tx = tid & 63, ty = tid >> 6;
        if (yb < 9) {
            __shared__ float t[64][65];
            const int l0 = xb * 64, ja0 = yb * 64;
            for (int r = ty; r < 64; r += 4) {
                int ja = ja0 + r, l = l0 + tx;
                if (ja < JA && l < NN) t[r][tx] = 2.0f * beta[(size_t)ja * NN + l];
            }
            __syncthreads();
            for (int r = ty; r < 64; r += 4) {
                int l = l0 + r, ja = ja0 + tx;
                if (l < NN && ja < JA)
                    Wf[(size_t)l * WROWH + ja] = __float2half(t[tx][r]);
            }
        } else {
            int l = xb * 64 + (tid & 63);
            int g = tid >> 6;                 // 0..3 -> j = 6g..6g+5
            if (l < NN) {
                __half* w = Wf + (size_t)l * WROWH + ALPH + g * 16;
                #pragma unroll
                for (int q = 0; q < 6; ++q) {
                    int j = g * 6 + q;
                    w[q]     = __float2half(alpha[(size_t)j * NN + l]);
                    w[6 + q] = __float2half(2.0f * beta[(size_t)(j * DD + j) * NN + l]);
                }
                w[12] = w[13] = w[14] = w[15] = __float2half(0.f);
            }
        }
    } else {
        const int pa = blockIdx.x - PREP_BLOCKS;       // 0..499
        const int wave = tid >> 6, lane = tid & 63;
        const int l = pa * 4 + wave;                   // 0..1999 (row owner)
        float xl[DD];
        {
            const float* xr = x + (size_t)l * DD;
            #pragma unroll
            for (int k = 0; k < DD; ++k) xl[k] = xr[k];
        }
        unsigned short* row = idx + (size_t)l * IDXCAP;
        int base = 0;
        for (int c = 0; c < 32; ++c) {
            int i = c * 64 + lane;
            bool valid = i < NN;
            int ic = valid ? i : 0;
            const float4* xv = reinterpret_cast<const float4*>(x + (size_t)ic * DD);
            float S = 0.f, m2 = 0.f;
            #pragma unroll
            for (int q = 0; q < 6; ++q) {
                float4 v = xv[q];
                float d0 = v.x - xl[4*q+0], d1 = v.y - xl[4*q+1];
                float d2 = v.z - xl[4*q+2], d3 = v.w - xl[4*q+3];
                d0 *= d0; d1 *= d1; d2 *= d2; d3 *= d3;
                S += (d0 + d1) + (d2 + d3);
                m2 = fmaxf(m2, fmaxf(fmaxf(d0, d1), fmaxf(d2, d3)));
            }
            bool pred = valid && (S - m2 <= THRESH);
            unsigned long long mask = __ballot(pred);
            if (pred) {
                int rank = __popcll(mask & ((1ull << lane) - 1ull));
                row[base + rank] = (unsigned short)i;
            }
            base += __popcll(mask);
        }
        if (lane == 0) cnt[l] = base;
    }
}

// ================= pass B: block = one i; 4 waves = 4 jgroups; lanes = entries ==========
// All W reads are 16-B float4 (dwordx4); halves unpacked via bit-cast.
// Butterfly shfl_xor reduce; lane 0 writes out[i][6w..6w+6). Deterministic.
template <int J0>
__device__ __forceinline__ void waveB(const float* __restrict__ x,
                                      const __half* __restrict__ Wf,
                                      const unsigned short* __restrict__ row,
                                      int c, const float (&xi)[DD],
                                      int lane, float* __restrict__ out, int i) {
    constexpr int g = J0 / 6;
    float acc[6];
    #pragma unroll
    for (int q = 0; q < 6; ++q) acc[q] = 0.0f;

    #pragma unroll 1
    for (int e = lane; e < c; e += 64) {
        const int l = row[e];
        const float4* __restrict__ xv = reinterpret_cast<const float4*>(x + (size_t)l * DD);
        const float4* __restrict__ wv = reinterpret_cast<const float4*>(Wf + (size_t)l * WROWH);

        // tail: 2 x float4 -> alpha[6], diag[6]
        float4 ta = wv[72 + 2 * g];
        float4 tb = wv[72 + 2 * g + 1];
        float2 a01 = h2f(ta.x), a23 = h2f(ta.y), a45 = h2f(ta.z);
        float2 d01 = h2f(ta.w), d23 = h2f(tb.x), d45 = h2f(tb.y);
        float alp[6] = {a01.x, a01.y, a23.x, a23.y, a45.x, a45.y};
        float dia[6] = {d01.x, d01.y, d23.x, d23.y, d45.x, d45.y};

        float diff[DD];
        float negS = 0.f;
        #pragma unroll
        for (int q = 0; q < 6; ++q) {
            float4 vv = xv[q];
            float d0 = xi[4*q+0] - vv.x, d1 = xi[4*q+1] - vv.y;
            float d2 = xi[4*q+2] - vv.z, d3 = xi[4*q+3] - vv.w;
            diff[4*q+0] = d0; diff[4*q+1] = d1;
            diff[4*q+2] = d2; diff[4*q+3] = d3;
            negS = fmaf(-d0, d0, negS); negS = fmaf(-d1, d1, negS);
            negS = fmaf(-d2, d2, negS); negS = fmaf(-d3, d3, negS);
        }

        #pragma unroll
        for (int q = 0; q < 6; ++q) {
            const int j = J0 + q;                        // compile-time
            float dj = diff[j];
            float K = __expf(fmaf(dj, dj, negS));        // exp(diff_j^2 - S)
            float4 b0 = wv[j * 3 + 0];                   // 3 x dwordx4 = 24 halves
            float4 b1 = wv[j * 3 + 1];
            float4 b2 = wv[j * 3 + 2];
            float t0 = 0.f, t1 = 0.f, t2 = 0.f, t3 = 0.f;
            float2 p;
            p = h2f(b0.x); t0 = fmaf(p.x, diff[0],  t0); t1 = fmaf(p.y, diff[1],  t1);
            p = h2f(b0.y); t2 = fmaf(p.x, diff[2],  t2); t3 = fmaf(p.y, diff[3],  t3);
            p = h2f(b0.z); t0 = fmaf(p.x, diff[4],  t0); t1 = fmaf(p.y, diff[5],  t1);
            p = h2f(b0.w); t2 = fmaf(p.x, diff[6],  t2); t3 = fmaf(p.y, diff[7],  t3);
            p = h2f(b1.x); t0 = fmaf(p.x, diff[8],  t0); t1 = fmaf(p.y, diff[9],  t1);
            p = h2f(b1.y); t2 = fmaf(p.x, diff[10], t2); t3 = fmaf(p.y, diff[11], t3);
            p = h2f(b1.z); t0 = fmaf(p.x, diff[12], t0); t1 = fmaf(p.y, diff[13], t1);
            p = h2f(b1.w); t2 = fmaf(p.x, diff[14], t2); t3 = fmaf(p.y, diff[15], t3);
            p = h2f(b2.x); t0 = fmaf(p.x, diff[16], t0); t1 = fmaf(p.y, diff[17], t1);
            p = h2f(b2.y); t2 = fmaf(p.x, diff[18], t2); t3 = fmaf(p.y, diff[19], t3);
            p = h2f(b2.z); t0 = fmaf(p.x, diff[20], t0); t1 = fmaf(p.y, diff[21], t1);
            p = h2f(b2.w); t2 = fmaf(p.x, diff[22], t2); t3 = fmaf(p.y, diff[23], t3);
            float t = (t0 + t1) + (t2 + t3);
            t = fmaf(-dia[q], dj, t);                    // drop a==j
            acc[q] += K * (alp[q] + t);
        }
    }

    // tree-reduce across 64 lanes (fixed order -> deterministic)
    #pragma unroll
    for (int q = 0; q < 6; ++q) {
        float v = acc[q];
        #pragma unroll
        for (int m = 1; m < 64; m <<= 1)
            v += __shfl_xor(v, m, 64);
        acc[q] = v;
    }
    if (lane == 0) {
        #pragma unroll
        for (int q = 0; q < 6; ++q)
            out[(size_t)i * DD + J0 + q] = acc[q];
    }
}

__global__ __launch_bounds__(256, 4) void k_passB(const float* __restrict__ x,
                                                  const __half* __restrict__ Wf,
                                                  const int* __restrict__ cnt,
                                                  const unsigned short* __restrict__ idx,
                                                  float* __restrict__ out) {
    const int i = blockIdx.x;                  // 0..1999
    const int wave = threadIdx.x >> 6, lane = threadIdx.x & 63;

    float xi[DD];
    {
        const float4* xr = reinterpret_cast<const float4*>(x + (size_t)i * DD);
        #pragma unroll
        for (int q = 0; q < 6; ++q) {
            float4 v = xr[q];
            xi[4*q+0] = v.x; xi[4*q+1] = v.y; xi[4*q+2] = v.z; xi[4*q+3] = v.w;
        }
    }
    const int c = cnt[i];
    const unsigned short* row = idx + (size_t)i * IDXCAP;

    if      (wave == 0) waveB<0 >(x, Wf, row, c, xi, lane, out, i);
    else if (wave == 1) waveB<6 >(x, Wf, row, c, xi, lane, out, i);
    else if (wave == 2) waveB<12>(x, Wf, row, c, xi, lane, out, i);
    else                waveB<18>(x, Wf, row, c, xi, lane, out, i);
}

// ================= dense fallback (never taken in practice; Wf layout) =================
template <int J0>
__device__ __forceinline__ void run_j6(const float* __restrict__ x,
                                       const __half* __restrict__ Wf,
                                       float* __restrict__ part,
                                       const float (&xi)[DD],
                                       int i, int lb, int l0, int l1) {
    constexpr int g = J0 / 6;
    float acc[6];
    #pragma unroll
    for (int q = 0; q < 6; ++q) acc[q] = 0.0f;
    #pragma unroll 1
    for (int l = l0; l < l1; ++l) {
        const __half* __restrict__ wrow = Wf + (size_t)l * WROWH;
        const float* __restrict__ xl = x + (size_t)l * DD;
        float diff[DD]; float negS = 0.0f;
        #pragma unroll
        for (int k = 0; k < DD; ++k) {
            float d = xi[k] - xl[k];
            diff[k] = d; negS = fmaf(-d, d, negS);
        }
        #pragma unroll
        for (int q = 0; q < 6; ++q) {
            const int j = J0 + q;
            float dj = diff[j];
            float K = __expf(fmaf(dj, dj, negS));
            float t = 0.f;
            #pragma unroll
            for (int a = 0; a < DD; ++a)
                t = fmaf(__half2float(wrow[j * DD + a]), diff[a], t);
            t = fmaf(-__half2float(wrow[ALPH + g * 16 + 6 + q]), dj, t);
            acc[q] = fmaf(K, __half2float(wrow[ALPH + g * 16 + q]) + t, acc[q]);
        }
    }
    if (i < NN) {
        #pragma unroll
        for (int q = 0; q < 6; ++q)
            part[((size_t)lb * DD + (J0+q)) * NN + i] = acc[q];
    }
}

__global__ __launch_bounds__(256, 4) void k_pass1_js(const float* __restrict__ x,
                                                     const __half* __restrict__ Wf,
                                                     float* __restrict__ part,
                                                     int lch) {
    const int tid  = threadIdx.x;
    const int wave = tid >> 6, lane = tid & 63;
    const int i  = blockIdx.x * 64 + lane;
    const int ic = i < NN ? i : NN - 1;
    const int lb = blockIdx.y;
    float xi[DD];
    {
        const float4* xr = reinterpret_cast<const float4*>(x + (size_t)ic * DD);
        #pragma unroll
        for (int q = 0; q < DD/4; ++q) {
            float4 v = xr[q];
            xi[4*q+0]=v.x; xi[4*q+1]=v.y; xi[4*q+2]=v.z; xi[4*q+3]=v.w;
        }
    }
    const int l0 = lb * lch;
    int l1 = l0 + lch; if (l1 > NN) l1 = NN;
    if      (wave == 0) run_j6<0 >(x, Wf, part, xi, i, lb, l0, l1);
    else if (wave == 1) run_j6<6 >(x, Wf, part, xi, i, lb, l0, l1);
    else if (wave == 2) run_j6<12>(x, Wf, part, xi, i, lb, l0, l1);
    else                run_j6<18>(x, Wf, part, xi, i, lb, l0, l1);
}

__global__ __launch_bounds__(256) void k_pass2t(const float* __restrict__ part,
                                                float* __restrict__ out, int lblk) {
    int m = blockIdx.x * 256 + threadIdx.x;
    if (m >= NN * DD) return;
    float s = 0.0f;
    for (int b = 0; b < lblk; ++b)
        s += part[(size_t)b * (NN * DD) + m];
    int j = m / NN, i = m - j * NN;
    out[(size_t)i * DD + j] = s;
}
// ================= end fallback =================

extern "C" void kernel_launch(void* const* d_in, const int* in_sizes, int n_in,
                              void* d_out, int out_size, void* d_ws, size_t ws_size,
                              hipStream_t stream) {
    const float* x     = (const float*)d_in[0];   // [2000, 24]
    const float* alpha = (const float*)d_in[1];   // [24, 2000]
    const float* beta  = (const float*)d_in[2];   // [24, 24, 2000]
    float* out = (float*)d_out;                   // [2000, 24]

    const size_t WBYTES    = (size_t)NN * WROWH * 2;               // 2,560,000
    const size_t CNT_OFF   = WBYTES;
    const size_t IDX_OFF   = CNT_OFF + 8192;
    const size_t IDXBYTES  = (size_t)NN * IDXCAP * 2;              // 8,192,000
    const size_t NEED = IDX_OFF + IDXBYTES;                        // ~10.8 MB

    __half* Wf = (__half*)d_ws;

    if (ws_size >= NEED) {
        int* cnt = (int*)((char*)d_ws + CNT_OFF);
        unsigned short* idx = (unsigned short*)((char*)d_ws + IDX_OFF);

        k_prepA<<<PREP_BLOCKS + 500, 256, 0, stream>>>(beta, alpha, x, Wf, cnt, idx);
        k_passB<<<NN, 256, 0, stream>>>(x, Wf, cnt, idx, out);
    } else {
        // dense fallback (unlikely: ws proven ~268 MB)
        const size_t SLAB = (size_t)NN * DD * 4;
        float* part = (float*)((char*)d_ws + IDX_OFF);
        int lblk = 32;
        while (lblk > 1 && IDX_OFF + (size_t)lblk * SLAB > ws_size) lblk >>= 1;
        int lch = (NN + lblk - 1) / lblk;
        int* cnt = (int*)((char*)d_ws + CNT_OFF);
        unsigned short* dummy = (unsigned short*)((char*)d_ws + CNT_OFF);
        k_prepA<<<PREP_BLOCKS, 256, 0, stream>>>(beta, alpha, x, Wf, cnt, dummy);
        k_pass1_js<<<dim3(32, lblk), 256, 0, stream>>>(x, Wf, part, lch);
        k_pass2t<<<(NN * DD + 255) / 256, 256, 0, stream>>>(part, out, lblk);
    }
}